// Round 3
// baseline (183.696 us; speedup 1.0000x reference)
//
#include <hip/hip_runtime.h>

// TDT loss, fixed shapes from setup_inputs():
#define TDT_B  8
#define TDT_T  256
#define TDT_U  64
#define TDT_U1 65
#define TDT_V1 513   // V+1, blank index = 512
#define TP     275   // 4 NEG pad slices + 256 + FIFO slack
#define NEGV  (-1e30f)
#define SIG    0.05f

// ws layout (floats):
//   PBD: float4[B][TP][U1]  = lpb(b,tau,u) + ld(b,tau,u,i)   (i in .x..w)
//   PYD: float4[B][TP][U]   = lpy(b,tau,u) + ld(b,tau,u,i)
#define OFF_PYD (TDT_B * TP * TDT_U1 * 4)            // 572000
#define OFF_LL  (OFF_PYD + TDT_B * TP * TDT_U * 4)   // (unused now)

__device__ __forceinline__ float lse4(float x0, float x1, float x2, float x3) {
  float m = fmaxf(fmaxf(x0, x1), fmaxf(x2, x3));
  float s = __expf(x0 - m) + __expf(x1 - m) + __expf(x2 - m) + __expf(x3 - m);
  return m + __logf(s);
}
__device__ __forceinline__ float lse8(float x0, float x1, float x2, float x3,
                                      float x4, float x5, float x6, float x7) {
  float ma = fmaxf(fmaxf(x0, x1), fmaxf(x2, x3));
  float mb = fmaxf(fmaxf(x4, x5), fmaxf(x6, x7));
  float m  = fmaxf(ma, mb);
  float s = __expf(x0 - m) + __expf(x1 - m) + __expf(x2 - m) + __expf(x3 - m)
          + __expf(x4 - m) + __expf(x5 - m) + __expf(x6 - m) + __expf(x7 - m);
  return m + __logf(s);
}

// Kernel 1: per-(b,t,u) row log-softmax over 513 labels (wave per row, float2
// loads with odd-row alignment shim), duration log-softmax over 4, write
// combined PBD/PYD float4 records. Also zero-inits out[0] for k_dp's atomics.
// IDEMPOTENT: pure function of inputs, distinct store addresses.
__global__ __launch_bounds__(256) void k_prep(
    const float* __restrict__ la, const float* __restrict__ da,
    const int* __restrict__ tgt, float* __restrict__ ws,
    float* __restrict__ out)
{
  if (blockIdx.x == 0 && threadIdx.x == 0) out[0] = 0.f;

  const int l = threadIdx.x & 63;
  const int r = (blockIdx.x << 2) + (threadIdx.x >> 6);   // row in [0, B*T*U1)
  const int u  = r % TDT_U1;
  const int bt = r / TDT_U1;
  const int t  = bt & (TDT_T - 1);
  const int b  = bt >> 8;

  const float* row = la + (size_t)r * TDT_V1;
  const int ofs = r & 1;                    // odd rows: shift by 1 for 8B align
  const float2* p2 = (const float2*)(row + ofs);
  float2 w[4];
#pragma unroll
  for (int k = 0; k < 4; ++k) w[k] = p2[l + (k << 6)];  // elems ofs+2l+128k+{0,1}
  const float extra = row[ofs ? 0 : 512];   // the one element outside the vec span

  float m = extra;
#pragma unroll
  for (int k = 0; k < 4; ++k) m = fmaxf(m, fmaxf(w[k].x, w[k].y));
#pragma unroll
  for (int off = 32; off; off >>= 1) m = fmaxf(m, __shfl_xor(m, off));
  float s = (l == 0) ? __expf(extra - m) : 0.f;
#pragma unroll
  for (int k = 0; k < 4; ++k) s += __expf(w[k].x - m) + __expf(w[k].y - m);
#pragma unroll
  for (int off = 32; off; off >>= 1) s += __shfl_xor(s, off);
  const float lse = m + __logf(s);

  // duration log-softmax (uniform per wave)
  const float4 dv = *(const float4*)(da + ((size_t)r << 2));
  const float m4 = fmaxf(fmaxf(dv.x, dv.y), fmaxf(dv.z, dv.w));
  const float l4 = m4 + __logf(__expf(dv.x - m4) + __expf(dv.y - m4) +
                               __expf(dv.z - m4) + __expf(dv.w - m4));
  const float d0 = dv.x - l4, d1 = dv.y - l4, d2 = dv.z - l4, d3 = dv.w - l4;

  float4* PBD4 = (float4*)ws;
  float4* PYD4 = (float4*)(ws + OFF_PYD);

  const int tp = t + 4;
  // blank logit = elem 512: ofs==0 -> extra (owner lane 0); ofs==1 -> w[3].y (lane 63)
  const float xb = ofs ? w[3].y : extra;
  if (l == (ofs ? 63 : 0)) {
    const float pb = xb - lse - SIG;
    PBD4[(b * TP + tp) * TDT_U1 + u] = make_float4(pb + d0, pb + d1, pb + d2, pb + d3);
  }

  // target gather (exactly one lane owns it); static indices only
  const int tg = (u < TDT_U) ? tgt[b * TDT_U + u] : -1;   // tg in [0,512)
  bool own = false; float vt = 0.f;
#pragma unroll
  for (int k = 0; k < 4; ++k) {
    const int base = ofs + ((l + (k << 6)) << 1);
    if (base == tg)     { vt = w[k].x; own = true; }
    if (base + 1 == tg) { vt = w[k].y; own = true; }
  }
  if (ofs && tg == 0 && l == 0) { vt = extra; own = true; }
  if (own) {
    const float py = vt - lse - SIG;
    PYD4[(b * TP + tp) * TDT_U + u] = make_float4(py + d0, py + d1, py + d2, py + d3);
  }

  // NEG pads for tau < 0 (slices tp = 0..3): lpX + ld = 2*NEG, matching ref lag pads
  if (t < 4 && l == 0) {
    const float nn = NEGV + NEGV;
    const float4 n4 = make_float4(nn, nn, nn, nn);
    PBD4[(b * TP + t) * TDT_U1 + u] = n4;
    if (u < TDT_U) PYD4[(b * TP + t) * TDT_U + u] = n4;
  }
}

// Kernel 2: forward DP. One wave per b. Lane l owns alpha[.][l]; the u=64
// column rides the c-regs (lane 63's view is the real one). 15-slot FIFO of
// NAMED float4 scalars (no arrays -> provably registers), 12-step lookahead.
__global__ __launch_bounds__(64, 1) void k_dp(
    const float* __restrict__ ws, float* __restrict__ out)
{
  const int b = blockIdx.x;
  const int l = threadIdx.x;
  const float4* PBD4 = (const float4*)ws + (size_t)b * (TP * TDT_U1);
  const float4* PYD4 = (const float4*)(ws + OFF_PYD) + (size_t)b * (TP * TDT_U);

  float4 B0,B1,B2,B3,B4,B5,B6,B7,B8,B9,B10,B11,B12,B13,B14;
  float4 Y0,Y1,Y2,Y3,Y4,Y5,Y6,Y7,Y8,Y9,Y10,Y11,Y12,Y13,Y14;
  float4 G0,G1,G2,G3,G4,G5,G6,G7,G8,G9,G10,G11,G12,G13,G14;

#define LOADSLOT(S, tpi) do {                \
    const int _tp = (tpi);                   \
    B##S = PBD4[_tp * TDT_U1 + l];           \
    Y##S = PYD4[_tp * TDT_U  + l];           \
    G##S = PBD4[_tp * TDT_U1 + 64];          \
  } while (0)

  // preload slices 1..15 into slots (slice % 15)
  LOADSLOT(1, 1);  LOADSLOT(2, 2);  LOADSLOT(3, 3);  LOADSLOT(4, 4);
  LOADSLOT(5, 5);  LOADSLOT(6, 6);  LOADSLOT(7, 7);  LOADSLOT(8, 8);
  LOADSLOT(9, 9);  LOADSLOT(10,10); LOADSLOT(11,11); LOADSLOT(12,12);
  LOADSLOT(13,13); LOADSLOT(14,14); LOADSLOT(0, 15);

  float a1 = (l == 0) ? 0.f : NEGV, a2 = NEGV, a3 = NEGV, a4 = NEGV;
  float c1 = NEGV, c2 = NEGV, c3 = NEGV, c4 = NEGV;

  // step t: slot(t+3).x/.y/.z/.w hold slices t+3,t+2,t+1,t (durations 1..4)
#define STEP(S0,S1,S2,S3, TPL) do {                                          \
    float ly0 = a1 + Y##S0.x, ly1 = a2 + Y##S1.y,                            \
          ly2 = a3 + Y##S2.z, ly3 = a4 + Y##S3.w;                            \
    float m0 = __shfl_up(ly0, 1), m1 = __shfl_up(ly1, 1),                    \
          m2 = __shfl_up(ly2, 1), m3 = __shfl_up(ly3, 1);                    \
    if (l == 0) { m0 = NEGV; m1 = NEGV; m2 = NEGV; m3 = NEGV; }              \
    float n0 = a1 + B##S0.x, n1 = a2 + B##S1.y,                              \
          n2 = a3 + B##S2.z, n3 = a4 + B##S3.w;                              \
    float q0 = c1 + G##S0.x, q1 = c2 + G##S1.y,                              \
          q2 = c3 + G##S2.z, q3 = c4 + G##S3.w;                              \
    float anew = lse8(n0, n1, n2, n3, m0, m1, m2, m3);                       \
    float cnew = lse8(q0, q1, q2, q3, ly0, ly1, ly2, ly3);                   \
    a4 = a3; a3 = a2; a2 = a1; a1 = anew;                                    \
    c4 = c3; c3 = c2; c2 = c1; c1 = cnew;                                    \
    LOADSLOT(S3, TPL);                                                       \
  } while (0)

  for (int tb = 1; tb < 256; tb += 15) {
    STEP(4,3,2,1,    tb + 15);
    STEP(5,4,3,2,    tb + 16);
    STEP(6,5,4,3,    tb + 17);
    STEP(7,6,5,4,    tb + 18);
    STEP(8,7,6,5,    tb + 19);
    STEP(9,8,7,6,    tb + 20);
    STEP(10,9,8,7,   tb + 21);
    STEP(11,10,9,8,  tb + 22);
    STEP(12,11,10,9, tb + 23);
    STEP(13,12,11,10,tb + 24);
    STEP(14,13,12,11,tb + 25);
    STEP(0,14,13,12, tb + 26);
    STEP(1,0,14,13,  tb + 27);
    STEP(2,1,0,14,   tb + 28);
    STEP(3,2,1,0,    tb + 29);
  }

  if (l == 63) {
    // ll = LSE_i( alpha[256-d][64] + lpb[256-d,64] + ld[256-d,64,i] ), tp = 259-i
    const float t0 = c1 + PBD4[259 * TDT_U1 + 64].x;
    const float t1 = c2 + PBD4[258 * TDT_U1 + 64].y;
    const float t2 = c3 + PBD4[257 * TDT_U1 + 64].z;
    const float t3 = c4 + PBD4[256 * TDT_U1 + 64].w;
    const float ll = lse4(t0, t1, t2, t3);
    atomicAdd(out, ll * (-1.0f / TDT_B));
  }
#undef STEP
#undef LOADSLOT
}

extern "C" void kernel_launch(void* const* d_in, const int* in_sizes, int n_in,
                              void* d_out, int out_size, void* d_ws, size_t ws_size,
                              hipStream_t stream)
{
  const float* la = (const float*)d_in[0];   // label_acts    (B,T,U+1,V+1) f32
  const float* da = (const float*)d_in[1];   // duration_acts (B,T,U+1,D)   f32
  const int*   tg = (const int*)d_in[2];     // targets       (B,U)         i32
  float* ws  = (float*)d_ws;
  float* out = (float*)d_out;

  const int rows = TDT_B * TDT_T * TDT_U1;   // 133120
  // ATTRIBUTION EXPERIMENT: k_prep launched twice (idempotent).
  // R3 = 2*prep + dp;  R2 = prep + dp = 137 us  =>  prep = R3 - 137.
  k_prep<<<rows / 4, 256, 0, stream>>>(la, da, tg, ws, out);
  k_prep<<<rows / 4, 256, 0, stream>>>(la, da, tg, ws, out);
  k_dp  <<<TDT_B, 64, 0, stream>>>(ws, out);
}

// Round 4
// 130.082 us; speedup vs baseline: 1.4121x; 1.4121x over previous
//
#include <hip/hip_runtime.h>

// TDT loss, fixed shapes from setup_inputs():
#define TDT_B  8
#define TDT_T  256
#define TDT_U  64
#define TDT_U1 65
#define TDT_V1 513   // V+1, blank index = 512
#define TP     275   // 4 NEG pad slices + 256 + FIFO slack
#define NEGV  (-1e30f)
#define SIG    0.05f

// ws layout (floats):
//   PBD: float4[B][TP][U1]  = lpb(b,tau,u) + ld(b,tau,u,i)   (i in .x..w)
//   PYD: float4[B][TP][U]   = lpy(b,tau,u) + ld(b,tau,u,i)
#define OFF_PYD (TDT_B * TP * TDT_U1 * 4)            // 572000
#define OFF_LL  (OFF_PYD + TDT_B * TP * TDT_U * 4)   // (unused now)

__device__ __forceinline__ float lse4(float x0, float x1, float x2, float x3) {
  float m = fmaxf(fmaxf(x0, x1), fmaxf(x2, x3));
  float s = __expf(x0 - m) + __expf(x1 - m) + __expf(x2 - m) + __expf(x3 - m);
  return m + __logf(s);
}
__device__ __forceinline__ float lse8(float x0, float x1, float x2, float x3,
                                      float x4, float x5, float x6, float x7) {
  float ma = fmaxf(fmaxf(x0, x1), fmaxf(x2, x3));
  float mb = fmaxf(fmaxf(x4, x5), fmaxf(x6, x7));
  float m  = fmaxf(ma, mb);
  float s = __expf(x0 - m) + __expf(x1 - m) + __expf(x2 - m) + __expf(x3 - m)
          + __expf(x4 - m) + __expf(x5 - m) + __expf(x6 - m) + __expf(x7 - m);
  return m + __logf(s);
}

// Kernel 1: per-(b,t,u) row log-softmax over 513 labels (wave per row, float2
// loads with odd-row alignment shim), duration log-softmax over 4, write
// combined PBD/PYD float4 records. Also zero-inits out[0] for k_dp's atomics.
__global__ __launch_bounds__(256) void k_prep(
    const float* __restrict__ la, const float* __restrict__ da,
    const int* __restrict__ tgt, float* __restrict__ ws,
    float* __restrict__ out)
{
  if (blockIdx.x == 0 && threadIdx.x == 0) out[0] = 0.f;

  const int l = threadIdx.x & 63;
  const int r = (blockIdx.x << 2) + (threadIdx.x >> 6);   // row in [0, B*T*U1)
  const int u  = r % TDT_U1;
  const int bt = r / TDT_U1;
  const int t  = bt & (TDT_T - 1);
  const int b  = bt >> 8;

  const float* row = la + (size_t)r * TDT_V1;
  const int ofs = r & 1;                    // odd rows: shift by 1 for 8B align
  const float2* p2 = (const float2*)(row + ofs);
  float2 w[4];
#pragma unroll
  for (int k = 0; k < 4; ++k) w[k] = p2[l + (k << 6)];  // elems ofs+2l+128k+{0,1}
  const float extra = row[ofs ? 0 : 512];   // the one element outside the vec span

  float m = extra;
#pragma unroll
  for (int k = 0; k < 4; ++k) m = fmaxf(m, fmaxf(w[k].x, w[k].y));
#pragma unroll
  for (int off = 32; off; off >>= 1) m = fmaxf(m, __shfl_xor(m, off));
  float s = (l == 0) ? __expf(extra - m) : 0.f;
#pragma unroll
  for (int k = 0; k < 4; ++k) s += __expf(w[k].x - m) + __expf(w[k].y - m);
#pragma unroll
  for (int off = 32; off; off >>= 1) s += __shfl_xor(s, off);
  const float lse = m + __logf(s);

  // duration log-softmax (uniform per wave)
  const float4 dv = *(const float4*)(da + ((size_t)r << 2));
  const float m4 = fmaxf(fmaxf(dv.x, dv.y), fmaxf(dv.z, dv.w));
  const float l4 = m4 + __logf(__expf(dv.x - m4) + __expf(dv.y - m4) +
                               __expf(dv.z - m4) + __expf(dv.w - m4));
  const float d0 = dv.x - l4, d1 = dv.y - l4, d2 = dv.z - l4, d3 = dv.w - l4;

  float4* PBD4 = (float4*)ws;
  float4* PYD4 = (float4*)(ws + OFF_PYD);

  const int tp = t + 4;
  // blank logit = elem 512: ofs==0 -> extra (owner lane 0); ofs==1 -> w[3].y (lane 63)
  const float xb = ofs ? w[3].y : extra;
  if (l == (ofs ? 63 : 0)) {
    const float pb = xb - lse - SIG;
    PBD4[(b * TP + tp) * TDT_U1 + u] = make_float4(pb + d0, pb + d1, pb + d2, pb + d3);
  }

  // target gather (exactly one lane owns it); static indices only
  const int tg = (u < TDT_U) ? tgt[b * TDT_U + u] : -1;   // tg in [0,512)
  bool own = false; float vt = 0.f;
#pragma unroll
  for (int k = 0; k < 4; ++k) {
    const int base = ofs + ((l + (k << 6)) << 1);
    if (base == tg)     { vt = w[k].x; own = true; }
    if (base + 1 == tg) { vt = w[k].y; own = true; }
  }
  if (ofs && tg == 0 && l == 0) { vt = extra; own = true; }
  if (own) {
    const float py = vt - lse - SIG;
    PYD4[(b * TP + tp) * TDT_U + u] = make_float4(py + d0, py + d1, py + d2, py + d3);
  }

  // NEG pads for tau < 0 (slices tp = 0..3): lpX + ld = 2*NEG, matching ref lag pads
  if (t < 4 && l == 0) {
    const float nn = NEGV + NEGV;
    const float4 n4 = make_float4(nn, nn, nn, nn);
    PBD4[(b * TP + t) * TDT_U1 + u] = n4;
    if (u < TDT_U) PYD4[(b * TP + t) * TDT_U + u] = n4;
  }
}

// Kernel 2: forward DP. One wave per b. Lane l owns alpha[.][l]; the u=64
// column rides the c-regs (lane 63's view is the real one). 15-slot FIFO of
// NAMED float4 scalars, 12-step lookahead.
// CHANGE vs round 2/3: the u=64 "G" column had a wave-uniform address -> the
// compiler scalarized it to s_load (SMEM). SMEM shares lgkmcnt with the
// __shfl bpermutes and returns out-of-order, so every step's shfl wait
// drained a fresh ~600-cycle L3 s_load => ~800 cyc/step. Fix: stage all 275
// G float4s (4.4 KB) into LDS once, feed the G FIFO with ds_read_b128
// (in-order lgkmcnt, precise waits). No SMEM in the loop.
__global__ __launch_bounds__(64, 1) void k_dp(
    const float* __restrict__ ws, float* __restrict__ out)
{
  const int b = blockIdx.x;
  const int l = threadIdx.x;
  const float4* PBD4 = (const float4*)ws + (size_t)b * (TP * TDT_U1);
  const float4* PYD4 = (const float4*)(ws + OFF_PYD) + (size_t)b * (TP * TDT_U);

  __shared__ float4 gl[TP];        // G column: PBD[tp][u=64], 4.4 KB
  for (int i = l; i < TP; i += 64) gl[i] = PBD4[i * TDT_U1 + 64];
  __syncthreads();

  float4 B0,B1,B2,B3,B4,B5,B6,B7,B8,B9,B10,B11,B12,B13,B14;
  float4 Y0,Y1,Y2,Y3,Y4,Y5,Y6,Y7,Y8,Y9,Y10,Y11,Y12,Y13,Y14;
  float4 G0,G1,G2,G3,G4,G5,G6,G7,G8,G9,G10,G11,G12,G13,G14;

#define LOADSLOT(S, tpi) do {                \
    const int _tp = (tpi);                   \
    B##S = PBD4[_tp * TDT_U1 + l];           \
    Y##S = PYD4[_tp * TDT_U  + l];           \
    G##S = gl[_tp];                          \
  } while (0)

  // preload slices 1..15 into slots (slice % 15)
  LOADSLOT(1, 1);  LOADSLOT(2, 2);  LOADSLOT(3, 3);  LOADSLOT(4, 4);
  LOADSLOT(5, 5);  LOADSLOT(6, 6);  LOADSLOT(7, 7);  LOADSLOT(8, 8);
  LOADSLOT(9, 9);  LOADSLOT(10,10); LOADSLOT(11,11); LOADSLOT(12,12);
  LOADSLOT(13,13); LOADSLOT(14,14); LOADSLOT(0, 15);

  float a1 = (l == 0) ? 0.f : NEGV, a2 = NEGV, a3 = NEGV, a4 = NEGV;
  float c1 = NEGV, c2 = NEGV, c3 = NEGV, c4 = NEGV;

  // step t: slot holding slice t+3 supplies .x (d=1) ... slice t supplies .w (d=4)
#define STEP(S0,S1,S2,S3, TPL) do {                                          \
    float ly0 = a1 + Y##S0.x, ly1 = a2 + Y##S1.y,                            \
          ly2 = a3 + Y##S2.z, ly3 = a4 + Y##S3.w;                            \
    float m0 = __shfl_up(ly0, 1), m1 = __shfl_up(ly1, 1),                    \
          m2 = __shfl_up(ly2, 1), m3 = __shfl_up(ly3, 1);                    \
    if (l == 0) { m0 = NEGV; m1 = NEGV; m2 = NEGV; m3 = NEGV; }              \
    float n0 = a1 + B##S0.x, n1 = a2 + B##S1.y,                              \
          n2 = a3 + B##S2.z, n3 = a4 + B##S3.w;                              \
    float q0 = c1 + G##S0.x, q1 = c2 + G##S1.y,                              \
          q2 = c3 + G##S2.z, q3 = c4 + G##S3.w;                              \
    float anew = lse8(n0, n1, n2, n3, m0, m1, m2, m3);                       \
    float cnew = lse8(q0, q1, q2, q3, ly0, ly1, ly2, ly3);                   \
    a4 = a3; a3 = a2; a2 = a1; a1 = anew;                                    \
    c4 = c3; c3 = c2; c2 = c1; c1 = cnew;                                    \
    LOADSLOT(S3, TPL);                                                       \
  } while (0)

  for (int tb = 1; tb < 256; tb += 15) {
    STEP(4,3,2,1,    tb + 15);
    STEP(5,4,3,2,    tb + 16);
    STEP(6,5,4,3,    tb + 17);
    STEP(7,6,5,4,    tb + 18);
    STEP(8,7,6,5,    tb + 19);
    STEP(9,8,7,6,    tb + 20);
    STEP(10,9,8,7,   tb + 21);
    STEP(11,10,9,8,  tb + 22);
    STEP(12,11,10,9, tb + 23);
    STEP(13,12,11,10,tb + 24);
    STEP(14,13,12,11,tb + 25);
    STEP(0,14,13,12, tb + 26);
    STEP(1,0,14,13,  tb + 27);
    STEP(2,1,0,14,   tb + 28);
    STEP(3,2,1,0,    tb + 29);
  }

  if (l == 63) {
    // ll = LSE_i( alpha[256-d][64] + lpb[256-d,64] + ld[256-d,64,i] ), tp = 259-i
    const float t0 = c1 + gl[259].x;
    const float t1 = c2 + gl[258].y;
    const float t2 = c3 + gl[257].z;
    const float t3 = c4 + gl[256].w;
    const float ll = lse4(t0, t1, t2, t3);
    atomicAdd(out, ll * (-1.0f / TDT_B));
  }
#undef STEP
#undef LOADSLOT
}

extern "C" void kernel_launch(void* const* d_in, const int* in_sizes, int n_in,
                              void* d_out, int out_size, void* d_ws, size_t ws_size,
                              hipStream_t stream)
{
  const float* la = (const float*)d_in[0];   // label_acts    (B,T,U+1,V+1) f32
  const float* da = (const float*)d_in[1];   // duration_acts (B,T,U+1,D)   f32
  const int*   tg = (const int*)d_in[2];     // targets       (B,U)         i32
  float* ws  = (float*)d_ws;
  float* out = (float*)d_out;

  const int rows = TDT_B * TDT_T * TDT_U1;   // 133120
  k_prep<<<rows / 4, 256, 0, stream>>>(la, da, tg, ws, out);
  k_dp  <<<TDT_B, 64, 0, stream>>>(ws, out);
}

// Round 6
// 88.428 us; speedup vs baseline: 2.0774x; 1.4711x over previous
//
#include <hip/hip_runtime.h>

// TDT loss, fixed shapes from setup_inputs():
#define TDT_B  8
#define TDT_T  256
#define TDT_U  64
#define TDT_U1 65
#define TDT_V1 513   // V+1, blank index = 512
#define TP     275   // 4 zero-pad slices + 256 + FIFO slack
#define SIG    0.05f
#define SHIFT  3.0f  // exponent shift PER TIME-STEP: duration-d weight carries SHIFT*d

// ws layout (floats):
//   WB: float4[B][TP][U1]  = exp(lpb + ld_i - SIG + SHIFT*(i+1))   (i in .x..w)
//   WY: float4[B][TP][U]   = exp(lpy + ld_i - SIG + SHIFT*(i+1))
#define OFF_PYD (TDT_B * TP * TDT_U1 * 4)            // 572000 floats

// Kernel 1: per-(b,t,u) row log-softmax over 513 labels (wave per row, float2
// loads with odd-row alignment shim), duration log-softmax over 4, write
// EXP-DOMAIN W records with per-duration scale e^{SHIFT*d}. Zero pads tau<0.
__global__ __launch_bounds__(256) void k_prep(
    const float* __restrict__ la, const float* __restrict__ da,
    const int* __restrict__ tgt, float* __restrict__ ws,
    float* __restrict__ out)
{
  if (blockIdx.x == 0 && threadIdx.x == 0) out[0] = 0.f;

  const int l = threadIdx.x & 63;
  const int r = (blockIdx.x << 2) + (threadIdx.x >> 6);   // row in [0, B*T*U1)
  const int u  = r % TDT_U1;
  const int bt = r / TDT_U1;
  const int t  = bt & (TDT_T - 1);
  const int b  = bt >> 8;

  const float* row = la + (size_t)r * TDT_V1;
  const int ofs = r & 1;                    // odd rows: shift by 1 for 8B align
  const float2* p2 = (const float2*)(row + ofs);
  float2 w[4];
#pragma unroll
  for (int k = 0; k < 4; ++k) w[k] = p2[l + (k << 6)];  // elems ofs+2l+128k+{0,1}
  const float extra = row[ofs ? 0 : 512];   // the one element outside the vec span

  float m = extra;
#pragma unroll
  for (int k = 0; k < 4; ++k) m = fmaxf(m, fmaxf(w[k].x, w[k].y));
#pragma unroll
  for (int off = 32; off; off >>= 1) m = fmaxf(m, __shfl_xor(m, off));
  float s = (l == 0) ? __expf(extra - m) : 0.f;
#pragma unroll
  for (int k = 0; k < 4; ++k) s += __expf(w[k].x - m) + __expf(w[k].y - m);
#pragma unroll
  for (int off = 32; off; off >>= 1) s += __shfl_xor(s, off);
  const float lse = m + __logf(s);

  // duration log-softmax (uniform per wave)
  const float4 dv = *(const float4*)(da + ((size_t)r << 2));
  const float m4 = fmaxf(fmaxf(dv.x, dv.y), fmaxf(dv.z, dv.w));
  const float l4 = m4 + __logf(__expf(dv.x - m4) + __expf(dv.y - m4) +
                               __expf(dv.z - m4) + __expf(dv.w - m4));
  // per-duration: ld_i - l4 + SHIFT*(i+1)  (scale-consistent exp domain)
  const float d0 = dv.x - l4 + SHIFT * 1.0f;
  const float d1 = dv.y - l4 + SHIFT * 2.0f;
  const float d2 = dv.z - l4 + SHIFT * 3.0f;
  const float d3 = dv.w - l4 + SHIFT * 4.0f;

  float4* WB4 = (float4*)ws;
  float4* WY4 = (float4*)(ws + OFF_PYD);

  const int tp = t + 4;
  // blank logit = elem 512: ofs==0 -> extra (owner lane 0); ofs==1 -> w[3].y (lane 63)
  const float xb = ofs ? w[3].y : extra;
  if (l == (ofs ? 63 : 0)) {
    const float pb = xb - lse - SIG;
    WB4[(b * TP + tp) * TDT_U1 + u] =
        make_float4(__expf(pb + d0), __expf(pb + d1), __expf(pb + d2), __expf(pb + d3));
  }

  // target gather (exactly one lane owns it); static indices only
  const int tg = (u < TDT_U) ? tgt[b * TDT_U + u] : -1;   // tg in [0,512)
  bool own = false; float vt = 0.f;
#pragma unroll
  for (int k = 0; k < 4; ++k) {
    const int base = ofs + ((l + (k << 6)) << 1);
    if (base == tg)     { vt = w[k].x; own = true; }
    if (base + 1 == tg) { vt = w[k].y; own = true; }
  }
  if (ofs && tg == 0 && l == 0) { vt = extra; own = true; }
  if (own) {
    const float py = vt - lse - SIG;
    WY4[(b * TP + tp) * TDT_U + u] =
        make_float4(__expf(py + d0), __expf(py + d1), __expf(py + d2), __expf(py + d3));
  }

  // zero pads for tau < 0 (slices tp = 0..3): exp(-inf) = 0
  if (t < 4 && l == 0) {
    const float4 z4 = make_float4(0.f, 0.f, 0.f, 0.f);
    WB4[(b * TP + t) * TDT_U1 + u] = z4;
    if (u < TDT_U) WY4[(b * TP + t) * TDT_U + u] = z4;
  }
}

// Kernel 2: forward DP in the scaled-exponential domain (linear recurrence:
// 8 FMAs + 4 product-shuffles per step, no exp/log/max on the chain).
// One wave per b, 8 blocks (one CU each, chain-bound). Lane l owns A[.][l];
// u=64 column rides the c-regs (lane 63's view is real). 15-slot FIFO of
// NAMED float4 registers, ~12-step vmcnt lookahead. Renorm once per 15-step
// block by max of two band probes (lanes t/8, t/4); exact bookkeeping in L.
// A_t(u) = exp(alpha_t(u) + SHIFT*t - L)  -- scale-consistent because W
// component i carries e^{SHIFT*(i+1)}.
__global__ __launch_bounds__(64, 1) void k_dp(
    const float* __restrict__ ws, float* __restrict__ out)
{
  const int b = blockIdx.x;
  const int l = threadIdx.x;
  const float4* WB4p = (const float4*)ws + (size_t)b * (TP * TDT_U1);
  const float4* WY4p = (const float4*)(ws + OFF_PYD) + (size_t)b * (TP * TDT_U);

  __shared__ float4 gl[TP];        // u=64 blank column, 4.4 KB
  for (int i = l; i < TP; i += 64) gl[i] = WB4p[i * TDT_U1 + 64];
  __syncthreads();

  float4 B0,B1,B2,B3,B4,B5,B6,B7,B8,B9,B10,B11,B12,B13,B14;
  float4 Y0,Y1,Y2,Y3,Y4,Y5,Y6,Y7,Y8,Y9,Y10,Y11,Y12,Y13,Y14;
  float4 G0,G1,G2,G3,G4,G5,G6,G7,G8,G9,G10,G11,G12,G13,G14;

#define LOADSLOT(S, tpi) do {                \
    const int _tp = (tpi);                   \
    B##S = WB4p[_tp * TDT_U1 + l];           \
    Y##S = WY4p[_tp * TDT_U  + l];           \
    G##S = gl[_tp];                          \
  } while (0)

  // preload slices 1..15 into slots (slice % 15)
  LOADSLOT(1, 1);  LOADSLOT(2, 2);  LOADSLOT(3, 3);  LOADSLOT(4, 4);
  LOADSLOT(5, 5);  LOADSLOT(6, 6);  LOADSLOT(7, 7);  LOADSLOT(8, 8);
  LOADSLOT(9, 9);  LOADSLOT(10,10); LOADSLOT(11,11); LOADSLOT(12,12);
  LOADSLOT(13,13); LOADSLOT(14,14); LOADSLOT(0, 15);

  // A = exp(alpha + SHIFT*t - L); alpha0[0]=0 -> A=1 at u=0
  float a1 = (l == 0) ? 1.f : 0.f, a2 = 0.f, a3 = 0.f, a4 = 0.f;
  float c1 = 0.f, c2 = 0.f, c3 = 0.f, c4 = 0.f;
  float L = 0.f;                            // uniform log offset

  // step t: slot holding slice t+3 supplies .x (d=1) ... slice t supplies .w (d=4)
#define STEP(S0,S1,S2,S3, TPL) do {                                          \
    float ly0 = a1 * Y##S0.x, ly1 = a2 * Y##S1.y,                            \
          ly2 = a3 * Y##S2.z, ly3 = a4 * Y##S3.w;                            \
    float m0 = __shfl_up(ly0, 1), m1 = __shfl_up(ly1, 1),                    \
          m2 = __shfl_up(ly2, 1), m3 = __shfl_up(ly3, 1);                    \
    if (l == 0) { m0 = 0.f; m1 = 0.f; m2 = 0.f; m3 = 0.f; }                  \
    float cnew = c1*G##S0.x + c2*G##S1.y + c3*G##S2.z + c4*G##S3.w           \
               + ((ly0 + ly1) + (ly2 + ly3));                                \
    float anew = a1*B##S0.x + a2*B##S1.y + a3*B##S2.z + a4*B##S3.w           \
               + ((m0 + m1) + (m2 + m3));                                    \
    a4 = a3; a3 = a2; a2 = a1; a1 = anew;                                    \
    c4 = c3; c3 = c2; c2 = c1; c1 = cnew;                                    \
    LOADSLOT(S3, TPL);                                                       \
  } while (0)

  for (int tb = 1; tb < 256; tb += 15) {
    if (tb != 1) {
      // uniform renorm: scale by 1/max(two band probes); exact bookkeeping in L
      const float r1 = __shfl(a1, tb >> 3);   // ~multiplicity peak (u ~ t/8)
      const float r2 = __shfl(a1, tb >> 2);   // band edge (u ~ t/4)
      const float rl = fmaxf(r1, r2);
      const float sc = (rl > 1e-30f) ? (1.0f / rl) : 1.0f;
      L -= __logf(sc);
      a1 *= sc; a2 *= sc; a3 *= sc; a4 *= sc;
      c1 *= sc; c2 *= sc; c3 *= sc; c4 *= sc;
    }
    STEP(4,3,2,1,    tb + 15);
    STEP(5,4,3,2,    tb + 16);
    STEP(6,5,4,3,    tb + 17);
    STEP(7,6,5,4,    tb + 18);
    STEP(8,7,6,5,    tb + 19);
    STEP(9,8,7,6,    tb + 20);
    STEP(10,9,8,7,   tb + 21);
    STEP(11,10,9,8,  tb + 22);
    STEP(12,11,10,9, tb + 23);
    STEP(13,12,11,10,tb + 24);
    STEP(14,13,12,11,tb + 25);
    STEP(0,14,13,12, tb + 26);
    STEP(1,0,14,13,  tb + 27);
    STEP(2,1,0,14,   tb + 28);
    STEP(3,2,1,0,    tb + 29);
  }

  if (l == 63) {
    // Every product c_d * WG_d carries e^{SHIFT*256 - L} uniformly:
    // ll = L - SHIFT*256 + log( sum_d C[256-d] * WG_d )
    const float sum = c1 * gl[259].x
                    + c2 * gl[258].y
                    + c3 * gl[257].z
                    + c4 * gl[256].w;
    const float ll = L - SHIFT * 256.0f + __logf(sum);
    atomicAdd(out, ll * (-1.0f / TDT_B));
  }
#undef STEP
#undef LOADSLOT
}

extern "C" void kernel_launch(void* const* d_in, const int* in_sizes, int n_in,
                              void* d_out, int out_size, void* d_ws, size_t ws_size,
                              hipStream_t stream)
{
  const float* la = (const float*)d_in[0];   // label_acts    (B,T,U+1,V+1) f32
  const float* da = (const float*)d_in[1];   // duration_acts (B,T,U+1,D)   f32
  const int*   tg = (const int*)d_in[2];     // targets       (B,U)         i32
  float* ws  = (float*)d_ws;
  float* out = (float*)d_out;

  const int rows = TDT_B * TDT_T * TDT_U1;   // 133120
  k_prep<<<rows / 4, 256, 0, stream>>>(la, da, tg, ws, out);
  k_dp  <<<TDT_B, 64, 0, stream>>>(ws, out);
}

// Round 7
// 82.115 us; speedup vs baseline: 2.2371x; 1.0769x over previous
//
#include <hip/hip_runtime.h>

// TDT loss, fixed shapes from setup_inputs():
#define TDT_B  8
#define TDT_T  256
#define TDT_U  64
#define TDT_U1 65
#define TDT_V1 513   // V+1, blank index = 512
#define TP     275   // 4 zero-pad slices + 256 + FIFO slack
#define SIG    0.05f
#define SHIFT  3.0f  // exponent shift PER TIME-STEP: duration-d weight carries SHIFT*d

// ws layout (floats):
//   WB: float4[B][TP][U1]  = exp(lpb + ld_i - SIG + SHIFT*(i+1))   (i in .x..w)
//   WY: float4[B][TP][U]   = exp(lpy + ld_i - SIG + SHIFT*(i+1))
#define OFF_PYD (TDT_B * TP * TDT_U1 * 4)            // 572000 floats

// Kernel 1: per-(b,t,u) row log-softmax over 513 labels (wave per row, float2
// loads with odd-row alignment shim), duration log-softmax over 4, write
// EXP-DOMAIN W records with per-duration scale e^{SHIFT*d}. Zero pads tau<0.
__global__ __launch_bounds__(256) void k_prep(
    const float* __restrict__ la, const float* __restrict__ da,
    const int* __restrict__ tgt, float* __restrict__ ws,
    float* __restrict__ out)
{
  if (blockIdx.x == 0 && threadIdx.x == 0) out[0] = 0.f;

  const int l = threadIdx.x & 63;
  const int r = (blockIdx.x << 2) + (threadIdx.x >> 6);   // row in [0, B*T*U1)
  const int u  = r % TDT_U1;
  const int bt = r / TDT_U1;
  const int t  = bt & (TDT_T - 1);
  const int b  = bt >> 8;

  const float* row = la + (size_t)r * TDT_V1;
  const int ofs = r & 1;                    // odd rows: shift by 1 for 8B align
  const float2* p2 = (const float2*)(row + ofs);
  float2 w[4];
#pragma unroll
  for (int k = 0; k < 4; ++k) w[k] = p2[l + (k << 6)];  // elems ofs+2l+128k+{0,1}
  const float extra = row[ofs ? 0 : 512];   // the one element outside the vec span

  float m = extra;
#pragma unroll
  for (int k = 0; k < 4; ++k) m = fmaxf(m, fmaxf(w[k].x, w[k].y));
#pragma unroll
  for (int off = 32; off; off >>= 1) m = fmaxf(m, __shfl_xor(m, off));
  float s = (l == 0) ? __expf(extra - m) : 0.f;
#pragma unroll
  for (int k = 0; k < 4; ++k) s += __expf(w[k].x - m) + __expf(w[k].y - m);
#pragma unroll
  for (int off = 32; off; off >>= 1) s += __shfl_xor(s, off);
  const float lse = m + __logf(s);

  // duration log-softmax (uniform per wave)
  const float4 dv = *(const float4*)(da + ((size_t)r << 2));
  const float m4 = fmaxf(fmaxf(dv.x, dv.y), fmaxf(dv.z, dv.w));
  const float l4 = m4 + __logf(__expf(dv.x - m4) + __expf(dv.y - m4) +
                               __expf(dv.z - m4) + __expf(dv.w - m4));
  // per-duration: ld_i - l4 + SHIFT*(i+1)  (scale-consistent exp domain)
  const float d0 = dv.x - l4 + SHIFT * 1.0f;
  const float d1 = dv.y - l4 + SHIFT * 2.0f;
  const float d2 = dv.z - l4 + SHIFT * 3.0f;
  const float d3 = dv.w - l4 + SHIFT * 4.0f;

  float4* WB4 = (float4*)ws;
  float4* WY4 = (float4*)(ws + OFF_PYD);

  const int tp = t + 4;
  // blank logit = elem 512: ofs==0 -> extra (owner lane 0); ofs==1 -> w[3].y (lane 63)
  const float xb = ofs ? w[3].y : extra;
  if (l == (ofs ? 63 : 0)) {
    const float pb = xb - lse - SIG;
    WB4[(b * TP + tp) * TDT_U1 + u] =
        make_float4(__expf(pb + d0), __expf(pb + d1), __expf(pb + d2), __expf(pb + d3));
  }

  // target gather (exactly one lane owns it); static indices only
  const int tg = (u < TDT_U) ? tgt[b * TDT_U + u] : -1;   // tg in [0,512)
  bool own = false; float vt = 0.f;
#pragma unroll
  for (int k = 0; k < 4; ++k) {
    const int base = ofs + ((l + (k << 6)) << 1);
    if (base == tg)     { vt = w[k].x; own = true; }
    if (base + 1 == tg) { vt = w[k].y; own = true; }
  }
  if (ofs && tg == 0 && l == 0) { vt = extra; own = true; }
  if (own) {
    const float py = vt - lse - SIG;
    WY4[(b * TP + tp) * TDT_U + u] =
        make_float4(__expf(py + d0), __expf(py + d1), __expf(py + d2), __expf(py + d3));
  }

  // zero pads for tau < 0 (slices tp = 0..3): exp(-inf) = 0
  if (t < 4 && l == 0) {
    const float4 z4 = make_float4(0.f, 0.f, 0.f, 0.f);
    WB4[(b * TP + t) * TDT_U1 + u] = z4;
    if (u < TDT_U) WY4[(b * TP + t) * TDT_U + u] = z4;
  }
}

// DPP wave_shr:1 (ctrl 0x138), bound_ctrl=1 -> lane 0 reads 0. VALU-pipe
// lane shift (~4-8 cyc) replacing ds_bpermute (~120 cyc LDS round trip)
// on the serial t-chain. rocPRIM uses the same ctrl for CDNA scans.
__device__ __forceinline__ float shup1(float x) {
  const int r = __builtin_amdgcn_update_dpp(
      0, __float_as_int(x), 0x138, 0xf, 0xf, true);
  return __int_as_float(r);
}

// Kernel 2: forward DP in the scaled-exponential domain (linear recurrence:
// 8 FMAs + 4 DPP lane-shifts per step, no exp/log/max/LDS on the chain).
// One wave per b, 8 blocks (one CU each, chain-bound). Lane l owns A[.][l];
// u=64 column rides the c-regs (lane 63's view is real). 15-slot FIFO of
// NAMED float4 registers, ~12-step vmcnt lookahead. Renorm once per 15-step
// block by max of two band probes (lanes t/8, t/4); exact bookkeeping in L.
// A_t(u) = exp(alpha_t(u) + SHIFT*t - L)  -- scale-consistent because W
// component i carries e^{SHIFT*(i+1)}.
__global__ __launch_bounds__(64, 1) void k_dp(
    const float* __restrict__ ws, float* __restrict__ out)
{
  const int b = blockIdx.x;
  const int l = threadIdx.x;
  const float4* WB4p = (const float4*)ws + (size_t)b * (TP * TDT_U1);
  const float4* WY4p = (const float4*)(ws + OFF_PYD) + (size_t)b * (TP * TDT_U);

  __shared__ float4 gl[TP];        // u=64 blank column, 4.4 KB
  for (int i = l; i < TP; i += 64) gl[i] = WB4p[i * TDT_U1 + 64];
  __syncthreads();

  float4 B0,B1,B2,B3,B4,B5,B6,B7,B8,B9,B10,B11,B12,B13,B14;
  float4 Y0,Y1,Y2,Y3,Y4,Y5,Y6,Y7,Y8,Y9,Y10,Y11,Y12,Y13,Y14;
  float4 G0,G1,G2,G3,G4,G5,G6,G7,G8,G9,G10,G11,G12,G13,G14;

#define LOADSLOT(S, tpi) do {                \
    const int _tp = (tpi);                   \
    B##S = WB4p[_tp * TDT_U1 + l];           \
    Y##S = WY4p[_tp * TDT_U  + l];           \
    G##S = gl[_tp];                          \
  } while (0)

  // preload slices 1..15 into slots (slice % 15)
  LOADSLOT(1, 1);  LOADSLOT(2, 2);  LOADSLOT(3, 3);  LOADSLOT(4, 4);
  LOADSLOT(5, 5);  LOADSLOT(6, 6);  LOADSLOT(7, 7);  LOADSLOT(8, 8);
  LOADSLOT(9, 9);  LOADSLOT(10,10); LOADSLOT(11,11); LOADSLOT(12,12);
  LOADSLOT(13,13); LOADSLOT(14,14); LOADSLOT(0, 15);

  // A = exp(alpha + SHIFT*t - L); alpha0[0]=0 -> A=1 at u=0
  float a1 = (l == 0) ? 1.f : 0.f, a2 = 0.f, a3 = 0.f, a4 = 0.f;
  float c1 = 0.f, c2 = 0.f, c3 = 0.f, c4 = 0.f;
  float L = 0.f;                            // uniform log offset

  // step t: slot holding slice t+3 supplies .x (d=1) ... slice t supplies .w (d=4)
#define STEP(S0,S1,S2,S3, TPL) do {                                          \
    float ly0 = a1 * Y##S0.x, ly1 = a2 * Y##S1.y,                            \
          ly2 = a3 * Y##S2.z, ly3 = a4 * Y##S3.w;                            \
    float m0 = shup1(ly0), m1 = shup1(ly1),                                  \
          m2 = shup1(ly2), m3 = shup1(ly3);                                  \
    float cnew = c1*G##S0.x + c2*G##S1.y + c3*G##S2.z + c4*G##S3.w           \
               + ((ly0 + ly1) + (ly2 + ly3));                                \
    float anew = a1*B##S0.x + a2*B##S1.y + a3*B##S2.z + a4*B##S3.w           \
               + ((m0 + m1) + (m2 + m3));                                    \
    a4 = a3; a3 = a2; a2 = a1; a1 = anew;                                    \
    c4 = c3; c3 = c2; c2 = c1; c1 = cnew;                                    \
    LOADSLOT(S3, TPL);                                                       \
  } while (0)

  for (int tb = 1; tb < 256; tb += 15) {
    if (tb != 1) {
      // uniform renorm: scale by 1/max(two band probes); exact bookkeeping in L
      const float r1 = __shfl(a1, tb >> 3);   // ~multiplicity peak (u ~ t/8)
      const float r2 = __shfl(a1, tb >> 2);   // band edge (u ~ t/4)
      const float rl = fmaxf(r1, r2);
      const float sc = (rl > 1e-30f) ? (1.0f / rl) : 1.0f;
      L -= __logf(sc);
      a1 *= sc; a2 *= sc; a3 *= sc; a4 *= sc;
      c1 *= sc; c2 *= sc; c3 *= sc; c4 *= sc;
    }
    STEP(4,3,2,1,    tb + 15);
    STEP(5,4,3,2,    tb + 16);
    STEP(6,5,4,3,    tb + 17);
    STEP(7,6,5,4,    tb + 18);
    STEP(8,7,6,5,    tb + 19);
    STEP(9,8,7,6,    tb + 20);
    STEP(10,9,8,7,   tb + 21);
    STEP(11,10,9,8,  tb + 22);
    STEP(12,11,10,9, tb + 23);
    STEP(13,12,11,10,tb + 24);
    STEP(14,13,12,11,tb + 25);
    STEP(0,14,13,12, tb + 26);
    STEP(1,0,14,13,  tb + 27);
    STEP(2,1,0,14,   tb + 28);
    STEP(3,2,1,0,    tb + 29);
  }

  if (l == 63) {
    // Every product c_d * WG_d carries e^{SHIFT*256 - L} uniformly:
    // ll = L - SHIFT*256 + log( sum_d C[256-d] * WG_d )
    const float sum = c1 * gl[259].x
                    + c2 * gl[258].y
                    + c3 * gl[257].z
                    + c4 * gl[256].w;
    const float ll = L - SHIFT * 256.0f + __logf(sum);
    atomicAdd(out, ll * (-1.0f / TDT_B));
  }
#undef STEP
#undef LOADSLOT
}

extern "C" void kernel_launch(void* const* d_in, const int* in_sizes, int n_in,
                              void* d_out, int out_size, void* d_ws, size_t ws_size,
                              hipStream_t stream)
{
  const float* la = (const float*)d_in[0];   // label_acts    (B,T,U+1,V+1) f32
  const float* da = (const float*)d_in[1];   // duration_acts (B,T,U+1,D)   f32
  const int*   tg = (const int*)d_in[2];     // targets       (B,U)         i32
  float* ws  = (float*)d_ws;
  float* out = (float*)d_out;

  const int rows = TDT_B * TDT_T * TDT_U1;   // 133120
  k_prep<<<rows / 4, 256, 0, stream>>>(la, da, tg, ws, out);
  k_dp  <<<TDT_B, 64, 0, stream>>>(ws, out);
}